// Round 5
// baseline (291.488 us; speedup 1.0000x reference)
//
#include <hip/hip_runtime.h>
#include <hip/hip_bf16.h>
#include <math.h>

#define B_   128
#define Qn   30
#define Dn   200
#define En   300

typedef __attribute__((ext_vector_type(8))) short short8;
typedef __attribute__((ext_vector_type(4))) float floatx4;
typedef unsigned int u32;
typedef unsigned short u16;

typedef const __attribute__((address_space(1))) unsigned int* gas_ptr;
typedef __attribute__((address_space(3))) unsigned int* las_ptr;

static __device__ __forceinline__ void gld_lds16(const void* g, void* l) {
    __builtin_amdgcn_global_load_lds((gas_ptr)g, (las_ptr)l, 16, 0, 0);
}

static __device__ __forceinline__ u16 f2b(float x) {   // fp32 -> bf16 RNE
    union { float f; u32 u; } v; v.f = x;
    u32 r = v.u + 0x7FFFu + ((v.u >> 16) & 1u);
    return (u16)(r >> 16);
}
static __device__ __forceinline__ float bits2f(u32 u) {
    union { u32 u2; float f; } v; v.u2 = u; return v.f;
}

// ---------------------------------------------------------------------------
// Prep: weights -> bf16 Wt[6 tapmats][128 ch][320 K] (K zero-padded 300->320).
// tapmats: t0=w1; t1,2=w2 taps 0,1; t3,4,5=w3 taps 0,1,2.
// ---------------------------------------------------------------------------
__global__ void prep_w_kernel(const float* __restrict__ w1, const float* __restrict__ w2,
                              const float* __restrict__ w3, u16* __restrict__ Wt) {
    int idx = blockIdx.x * 256 + threadIdx.x;           // < 6*128*320 = 245760
    if (idx >= 6*128*320) return;
    int t = idx / 40960;
    int rem = idx - t * 40960;
    int c = rem / 320;
    int e = rem - c * 320;
    float v = 0.f;
    if (e < 300) {
        if (t == 0)       v = w1[c*300 + e];
        else if (t <= 2)  v = w2[(c*300 + e)*2 + (t - 1)];
        else              v = w3[(c*300 + e)*3 + (t - 3)];
    }
    Wt[idx] = f2b(v);
}

// ---------------------------------------------------------------------------
// Conv: one block = 64 output positions of one batch item. grid (4, B).
//   tiles 0..2: d outputs tile*64 .. tile*64+63 (A rows = tokens tile*64..+65)
//   tile 3:     d outputs 192..199 (A rows 0..9 = tokens 192..201, zero >=200)
//               A rows 10..15 zero (guard gap)
//               q outputs 0..29 (A rows 16..47 = q tokens 0..31, zero >=30)
//               A rows 48..65 zero
// K-loop: ss=0..9 x unrolled h=0,1 half-slices (24 KB each), double-buffered,
// prefetch issued before the MFMAs of the current slice. ALL acc indices are
// compile-time constants (R4's runtime h index forced acc into scratch:
// 569 MB of spill writes, MfmaUtil 5%).
// LDS: A [66][328]u16 = 43296 | B0 24576 | B1 24576  (= 92448 dynamic)
// ---------------------------------------------------------------------------
__global__ __launch_bounds__(256, 1) void conv_kernel(
    const int* __restrict__ qtok, const int* __restrict__ dtok,
    const float* __restrict__ emb, const u16* __restrict__ Wt,
    const float* __restrict__ b1, const float* __restrict__ b2, const float* __restrict__ b3,
    u16* __restrict__ qg, u16* __restrict__ dg,
    float* __restrict__ invnq, float* __restrict__ invnd)
{
    extern __shared__ char smem[];
    char* As  = smem;                      // [66][328] u16 = 43296
    char* Bb0 = smem + 43296;              // 24576
    char* Bb1 = smem + 67872;              // 24576
    __shared__ int toks[66];

    const int tid = threadIdx.x;
    const int b = blockIdx.y;
    const int tile = blockIdx.x;

    const int wv = tid >> 6, lane = tid & 63;
    const int l15 = lane & 15, qd4 = lane >> 4;
    const int lrow = lane >> 2, lchk = lane & 3;

    // per-lane global offsets for this wave's 6 DMA instructions (within a half-slice)
    u32 goff[6];
    #pragma unroll
    for (int i = 0; i < 6; ++i) {
        int lr = (wv*6 + i)*16 + lrow;                 // 0..383
        goff[i] = (u32)((((lr >> 6)*128 + (lr & 63))*640) + lchk*16);
    }
    // issue slice 0 immediately
    {
        const char* base = (const char*)Wt;
        #pragma unroll
        for (int i = 0; i < 6; ++i)
            gld_lds16(base + goff[i], Bb0 + (wv*6 + i)*1024);
    }

    // token map
    if (tid < 66) {
        int tok = -1;
        if (tile < 3) {
            tok = dtok[b*Dn + tile*64 + tid];          // tile*64+65 <= 193 < 200
        } else {
            if (tid < 8)                    tok = dtok[b*Dn + 192 + tid];
            else if (tid >= 16 && tid < 46) tok = qtok[b*Qn + (tid - 16)];
        }
        toks[tid] = tok;
    }
    __syncthreads();

    // gather embeddings -> bf16 A tile
    for (int f = tid; f < 66*75; f += 256) {
        int row = f / 75, e4 = f - row*75;
        int t = toks[row];
        float4 v = make_float4(0.f, 0.f, 0.f, 0.f);
        if (t >= 0) v = *(const float4*)(emb + t*En + e4*4);
        u16* p = (u16*)(As + row*656 + e4*8);
        p[0] = f2b(v.x); p[1] = f2b(v.y); p[2] = f2b(v.z); p[3] = f2b(v.w);
    }
    for (int f = tid; f < 66*14; f += 256) {           // zero K cols 300..327
        int row = f / 14, cc = f - row*14;
        *(u32*)(As + row*656 + 600 + cc*4) = 0u;
    }

    floatx4 acc[3][8];
    #pragma unroll
    for (int g = 0; g < 3; ++g)
        #pragma unroll
        for (int nt = 0; nt < 8; ++nt)
            acc[g][nt] = (floatx4){0.f, 0.f, 0.f, 0.f};

    static const int TG[6] = {0,1,1,2,2,2};
    static const int TJ[6] = {0,0,1,0,1,2};

    short8 af[3];
    for (int ss = 0; ss < 10; ++ss) {
        #pragma unroll
        for (int h = 0; h < 2; ++h) {                  // h is compile-time after unroll
            const int s = 2*ss + h;
            __syncthreads();                           // slice s drained & visible
            if (s < 19) {                              // prefetch slice s+1
                const int s1 = s + 1;
                const char* base = (const char*)Wt + (s1 >> 1)*64 + (s1 & 1)*40960;
                char* lb = (s1 & 1) ? Bb1 : Bb0;
                #pragma unroll
                for (int i = 0; i < 6; ++i)
                    gld_lds16(base + goff[i], lb + (wv*6 + i)*1024);
            }
            if (h == 0) {
                #pragma unroll
                for (int j = 0; j < 3; ++j)
                    af[j] = *(const short8*)(As + (wv*16 + j + l15)*656 + ss*64 + qd4*16);
            }
            const char* Bc = h ? Bb1 : Bb0;
            #pragma unroll
            for (int t = 0; t < 6; ++t) {
                #pragma unroll
                for (int nh = 0; nh < 4; ++nh) {
                    short8 bf = *(const short8*)(Bc + (t*64 + nh*16 + l15)*64 + qd4*16);
                    acc[TG[t]][h*4 + nh] = __builtin_amdgcn_mfma_f32_16x16x32_bf16(
                        af[TJ[t]], bf, acc[TG[t]][h*4 + nh], 0, 0, 0);
                }
            }
        }
    }
    __syncthreads();                                   // frag reads done; overlay Gs

    // epilogue per gram: bias+relu+bf16 -> Gs[64][136] -> norms + copy out
    u16* Gs = (u16*)Bb0;
    #pragma unroll
    for (int g = 0; g < 3; ++g) {
        __syncthreads();
        const float* bp = (g == 0) ? b1 : ((g == 1) ? b2 : b3);
        #pragma unroll
        for (int nh = 0; nh < 8; ++nh) {
            int c = nh*16 + l15;
            float bias = bp[c];
            #pragma unroll
            for (int i = 0; i < 4; ++i) {
                int m = wv*16 + qd4*4 + i;
                Gs[m*136 + c] = f2b(fmaxf(acc[g][nh][i] + bias, 0.f));
            }
        }
        __syncthreads();
        if (tid < 64) {                                // inverse norms from bf16 values
            const char* rp = (const char*)Gs + tid*272;
            float ssum = 0.f;
            #pragma unroll
            for (int t16 = 0; t16 < 16; ++t16) {
                uint4 u = *(const uint4*)(rp + t16*16);
                float x;
                x = bits2f(u.x << 16); ssum += x*x;  x = bits2f(u.x & 0xffff0000u); ssum += x*x;
                x = bits2f(u.y << 16); ssum += x*x;  x = bits2f(u.y & 0xffff0000u); ssum += x*x;
                x = bits2f(u.z << 16); ssum += x*x;  x = bits2f(u.z & 0xffff0000u); ssum += x*x;
                x = bits2f(u.w << 16); ssum += x*x;  x = bits2f(u.w & 0xffff0000u); ssum += x*x;
            }
            float inv = 1.f / (sqrtf(ssum) + 1e-13f);
            if (tile < 3) {
                invnd[(g*B_ + b)*208 + tile*64 + tid] = inv;
            } else {
                if (tid < 8)                    invnd[(g*B_ + b)*208 + 192 + tid] = inv;
                else if (tid >= 16 && tid < 46) invnq[(g*B_ + b)*32 + (tid - 16)] = inv;
            }
        }
        {
            int ch = tid & 15, r0 = tid >> 4;
            #pragma unroll
            for (int p = 0; p < 4; ++p) {
                int r = p*16 + r0;
                uint4 v = *(const uint4*)((const char*)Gs + r*272 + ch*16);
                if (tile < 3) {
                    *(uint4*)(dg + ((g*B_ + b)*208 + tile*64 + r)*128 + ch*8) = v;
                } else {
                    if (r < 8)                  *(uint4*)(dg + ((g*B_ + b)*208 + 192 + r)*128 + ch*8) = v;
                    else if (r >= 16 && r < 46) *(uint4*)(qg + ((g*B_ + b)*32 + (r - 16))*128 + ch*8) = v;
                }
            }
        }
    }
}

// ---------------------------------------------------------------------------
// Pool: block = (dj*2+chunk, b); grid (6, B). d-chunk in LDS, q-frags from L2,
// qi-loop keeps registers small. RBF via exp-chain: e_{k+1} = e_k * r * C_k
// (r = exp(-20c)), 3 transcendentals instead of 11. Per-chunk partials -> pkg.
// Unwritten-global poison handling: qg rows 30/31 & invq rows 30/31 masked by
// vq=0; dg/invnd rows >= Dn zero-staged / sign-masked.
// ---------------------------------------------------------------------------
__global__ __launch_bounds__(256, 3) void pool_kernel(
    const u16* __restrict__ qg, const u16* __restrict__ dg,
    const float* __restrict__ invnq, const float* __restrict__ invnd,
    const int* __restrict__ qtok, const int* __restrict__ dtok,
    float* __restrict__ pkg)
{
    __shared__ __align__(16) u16 dsb[112*136];
    __shared__ float pk[96*12];
    __shared__ float invq[96];
    __shared__ __align__(16) float invd[112];

    const int tid = threadIdx.x;
    const int b = blockIdx.y;
    const int dj = blockIdx.x >> 1, chunk = blockIdx.x & 1;
    const int base_r = chunk * 112;
    const int RN = chunk ? 96 : 112;
    const int NT = chunk ? 6 : 7;

    const int wv = tid >> 6, lane = tid & 63;
    const int l15 = lane & 15, qd4 = lane >> 4;

    for (int idx = tid; idx < RN*16; idx += 256) {
        int r = idx >> 4, ch = idx & 15;
        int gr = base_r + r;
        uint4 v = make_uint4(0u, 0u, 0u, 0u);
        if (gr < Dn) v = *(const uint4*)(dg + ((dj*B_ + b)*208 + gr)*128 + ch*8);
        *(uint4*)((char*)dsb + r*272 + ch*16) = v;
    }
    if (tid < RN) {
        int gr = base_r + tid;
        float v = invnd[(dj*B_ + b)*208 + gr];
        bool ok = (gr < Dn) && (dtok[b*Dn + gr] > 0);
        invd[tid] = ok ? v : (-fabsf(v) - 1.0f);       // strictly negative if masked
    }
    if (tid < 96) {
        int qi = tid >> 5, qr = tid & 31;
        float v = invnq[(qi*B_ + b)*32 + qr];
        bool ok = (qr < Qn) && (qtok[b*Qn + qr] > 0);
        invq[tid] = ok ? v : 0.f;
    }
    for (int i = tid; i < 96*12; i += 256) pk[i] = 0.f;
    __syncthreads();

    // chain constants C_k = exp(10*(mu_k + mu_{k+1})), mu: 0.9,0.7,...,-0.9
    const float CkR[9] = {8886110.5f, 162754.79f, 2980.958f, 54.598150f, 1.0f,
                          0.018315639f, 3.3546263e-4f, 6.1442124e-6f, 1.1253517e-7f};

    for (int qi = 0; qi < 3; ++qi) {
        short8 qf[2][4];
        float vq[2];
        #pragma unroll
        for (int qt = 0; qt < 2; ++qt) {
            vq[qt] = invq[qi*32 + qt*16 + l15];
            #pragma unroll
            for (int ks = 0; ks < 4; ++ks)
                qf[qt][ks] = *(const short8*)(qg + ((qi*B_ + b)*32 + qt*16 + l15)*128 + ks*32 + qd4*8);
        }
        float pkl[2][11];
        #pragma unroll
        for (int qt = 0; qt < 2; ++qt)
            #pragma unroll
            for (int k = 0; k < 11; ++k) pkl[qt][k] = 0.f;

        for (int t = wv; t < NT; t += 4) {
            short8 af[4];
            #pragma unroll
            for (int ks = 0; ks < 4; ++ks)
                af[ks] = *(const short8*)((const char*)dsb + (t*16 + l15)*272 + ks*64 + qd4*16);
            floatx4 acc[2];
            acc[0] = (floatx4){0.f,0.f,0.f,0.f};
            acc[1] = (floatx4){0.f,0.f,0.f,0.f};
            #pragma unroll
            for (int ks = 0; ks < 4; ++ks)
                #pragma unroll
                for (int qt = 0; qt < 2; ++qt)
                    acc[qt] = __builtin_amdgcn_mfma_f32_16x16x32_bf16(af[ks], qf[qt][ks], acc[qt], 0, 0, 0);
            floatx4 iv4 = *(const floatx4*)(invd + t*16 + qd4*4);
            #pragma unroll
            for (int qt = 0; qt < 2; ++qt)
                #pragma unroll
                for (int i = 0; i < 4; ++i) {
                    float cs = acc[qt][i] * vq[qt] * iv4[i];
                    cs = (cs > 0.f) ? cs : 2.0f;       // masked/zero -> all kernels ~0
                    float t0 = cs - 1.0f;
                    float u  = cs - 0.9f;
                    float s0 = __expf(-500000.f * t0 * t0);   // k=0, sigma=0.001
                    float e  = __expf(-50.f * u * u);          // k=1, mu=0.9
                    float r  = __expf(-20.f * cs);
                    pkl[qt][0] += s0;
                    pkl[qt][1] += e;
                    #pragma unroll
                    for (int kk = 0; kk < 9; ++kk) {
                        e = e * r * CkR[kk];
                        pkl[qt][2 + kk] += e;
                    }
                }
        }
        #pragma unroll
        for (int qt = 0; qt < 2; ++qt)
            #pragma unroll
            for (int k = 0; k < 11; ++k) {
                float v = pkl[qt][k];
                v += __shfl_xor(v, 16);
                v += __shfl_xor(v, 32);
                if (qd4 == 0) atomicAdd(&pk[(qi*32 + qt*16 + l15)*12 + k], v);
            }
    }
    __syncthreads();
    {
        float* dst = pkg + ((chunk*3 + dj)*B_ + b)*1152;
        for (int i = tid; i < 1152; i += 256) dst[i] = pk[i];
    }
}

// ---------------------------------------------------------------------------
// Final: merge chunk partials, log-mask-sum over q, dense dot. grid = B blocks.
// ---------------------------------------------------------------------------
__global__ void final_kernel(const float* __restrict__ pkg,
                             const int* __restrict__ qtok,
                             const float* __restrict__ dw,
                             float* __restrict__ out) {
    __shared__ float feats[99];
    __shared__ float qmsk[32];
    const int b = blockIdx.x, tid = threadIdx.x;
    if (tid < 32) qmsk[tid] = (tid < Qn && qtok[b*Qn + tid] > 0) ? 1.f : 0.f;
    __syncthreads();
    if (tid < 99) {
        int combo = tid / 11, k = tid - combo*11;
        int qi = combo / 3, dj = combo - qi*3;
        const float* p0 = pkg + ((0*3 + dj)*B_ + b)*1152 + qi*32*12 + k;
        const float* p1 = pkg + ((1*3 + dj)*B_ + b)*1152 + qi*32*12 + k;
        float s = 0.f;
        for (int q = 0; q < Qn; ++q) {
            float v = p0[q*12] + p1[q*12];
            s += qmsk[q] * 0.01f * logf(fmaxf(v, 1e-10f));
        }
        feats[tid] = s;
    }
    __syncthreads();
    if (tid == 0) {
        float s = 0.f;
        for (int f = 0; f < 99; ++f) s += feats[f] * dw[f];
        out[b] = s;
    }
}

extern "C" void kernel_launch(void* const* d_in, const int* in_sizes, int n_in,
                              void* d_out, int out_size, void* d_ws, size_t ws_size,
                              hipStream_t stream) {
    const int*   qtok = (const int*)d_in[0];
    const int*   dtok = (const int*)d_in[1];
    const float* emb  = (const float*)d_in[2];
    const float* w1   = (const float*)d_in[3];
    const float* w2   = (const float*)d_in[4];
    const float* w3   = (const float*)d_in[5];
    const float* b1   = (const float*)d_in[6];
    const float* b2   = (const float*)d_in[7];
    const float* b3   = (const float*)d_in[8];
    const float* dw   = (const float*)d_in[9];
    float* out = (float*)d_out;

    char* w = (char*)d_ws;
    u16*   Wt    = (u16*)w;                      // 491,520 B
    u16*   qg    = (u16*)(w + 491520);           // 3*128*32*128*2  = 3,145,728
    u16*   dgm   = (u16*)(w + 3637248);          // 3*128*208*128*2 = 20,447,232
    float* invq_ = (float*)(w + 24084480);       // 49,152
    float* invd_ = (float*)(w + 24133632);       // 319,488
    float* pkg   = (float*)(w + 24453120);       // 3,538,944 -> total 27,992,064

    prep_w_kernel<<<960, 256, 0, stream>>>(w1, w2, w3, Wt);

    const int conv_lds = 92448;
    hipFuncSetAttribute(reinterpret_cast<const void*>(conv_kernel),
                        hipFuncAttributeMaxDynamicSharedMemorySize, conv_lds);
    conv_kernel<<<dim3(4, B_), 256, conv_lds, stream>>>(
        qtok, dtok, emb, Wt, b1, b2, b3, qg, dgm, invq_, invd_);

    pool_kernel<<<dim3(6, B_), 256, 0, stream>>>(qg, dgm, invq_, invd_, qtok, dtok, pkg);

    final_kernel<<<B_, 128, 0, stream>>>(pkg, qtok, dw, out);
}

// Round 6
// 194.540 us; speedup vs baseline: 1.4983x; 1.4983x over previous
//
#include <hip/hip_runtime.h>
#include <hip/hip_bf16.h>
#include <math.h>

#define B_   128
#define Qn   30
#define Dn   200
#define En   300

typedef __attribute__((ext_vector_type(8))) short short8;
typedef __attribute__((ext_vector_type(4))) float floatx4;
typedef unsigned int u32;
typedef unsigned short u16;

typedef const __attribute__((address_space(1))) unsigned int* gas_ptr;
typedef __attribute__((address_space(3))) unsigned int* las_ptr;

static __device__ __forceinline__ void gld_lds16(const void* g, void* l) {
    __builtin_amdgcn_global_load_lds((gas_ptr)g, (las_ptr)l, 16, 0, 0);
}

static __device__ __forceinline__ u16 f2b(float x) {   // fp32 -> bf16 RNE
    union { float f; u32 u; } v; v.f = x;
    u32 r = v.u + 0x7FFFu + ((v.u >> 16) & 1u);
    return (u16)(r >> 16);
}
static __device__ __forceinline__ float bits2f(u32 u) {
    union { u32 u2; float f; } v; v.u2 = u; return v.f;
}

// ---------------------------------------------------------------------------
// prep_gather: fused (a) token gather -> bf16 A [128][256][320] (+2 zero rows)
//              (b) weight permute -> Wt2, per-gram DMA/frag-friendly layout:
//   gram g (ntap taps) at byte base Bg: [ks 10][j ntap][nt 8][q4 4][c16 16][k8 8] bf16
//   (inner 1024 B group is exactly lane*16 for lane = qd4*16 + l15)
// grid (24, 128): x<16 -> gather blocks (b=y, rows x*16..+15); x>=16 -> permute.
// ---------------------------------------------------------------------------
__global__ void prep_gather_kernel(
    const int* __restrict__ qtok, const int* __restrict__ dtok,
    const float* __restrict__ emb,
    const float* __restrict__ w1, const float* __restrict__ w2, const float* __restrict__ w3,
    u16* __restrict__ Ag, u16* __restrict__ Wt2)
{
    const int tid = threadIdx.x;
    if (blockIdx.x < 16) {
        const int b = blockIdx.y, c = blockIdx.x;
        __shared__ int toks[16];
        if (tid < 16) {
            int pos = c*16 + tid;
            int tok = -1;
            if (pos < Dn) tok = dtok[b*Dn + pos];
            else if (pos >= 208 && pos < 238) tok = qtok[b*Qn + (pos - 208)];
            toks[tid] = tok;
        }
        __syncthreads();
        #pragma unroll
        for (int i = 0; i < 5; ++i) {
            int f = tid + i*256;                     // < 1280 = 16 rows * 80 col4
            int r = f / 80, c4 = f - r*80;
            int t = toks[r];
            u16 o0=0,o1=0,o2=0,o3=0;
            if (t >= 0 && c4 < 75) {
                float4 v = *(const float4*)(emb + t*En + c4*4);
                o0=f2b(v.x); o1=f2b(v.y); o2=f2b(v.z); o3=f2b(v.w);
            }
            u16* p = Ag + ((b*256 + c*16 + r)*320 + c4*4);
            p[0]=o0; p[1]=o1; p[2]=o2; p[3]=o3;
        }
        if (b == 127 && c == 15 && tid < 160) {      // 2 zero pad rows (32768,32769)
            u16* p = Ag + (32768*320) + tid*4;
            p[0]=0; p[1]=0; p[2]=0; p[3]=0;
        }
    } else {
        // weight permute: one u16 per thread
        int p = ((blockIdx.x - 16)*128 + blockIdx.y)*256 + tid;
        if (p >= 245760) return;
        int g, ntap, o;
        if (p < 40960)       { g=0; ntap=1; o=p; }
        else if (p < 122880) { g=1; ntap=2; o=p-40960; }
        else                 { g=2; ntap=3; o=p-122880; }
        int ks = o / (ntap*4096);
        int r  = o - ks*(ntap*4096);
        int j  = r / 4096;
        int r2 = r & 4095;
        int nt = r2 >> 9;
        int r3 = r2 & 511;
        int q4 = r3 >> 7;
        int c16 = (r3 >> 3) & 15;
        int k8 = r3 & 7;
        int ch = nt*16 + c16;
        int e  = ks*32 + q4*8 + k8;
        float v = 0.f;
        if (e < En) {
            if (g == 0)      v = w1[ch*En + e];
            else if (g == 1) v = w2[(ch*En + e)*2 + j];
            else             v = w3[(ch*En + e)*3 + j];
        }
        Wt2[p] = f2b(v);
    }
}

// ---------------------------------------------------------------------------
// Conv GEMM: block = (tile, gram). 64 out rows x 128 ch, K=320, taps via
// A-frag row shifts. 4 waves = 2 mh x 2 nh (32 rows x 64 ch each, 2x4 acc).
// B-slices (ntap*8KB) single-buffered via global_load_lds; DMA exposure hidden
// by the co-resident block (LDS 66.3 KB -> 2 blocks/CU).
// LDS: A [66][328]u16 = 43296 | Bs 24576 (epilogue overlay Gs[64][136]u16).
// ---------------------------------------------------------------------------
template<int NTAP>
static __device__ __forceinline__ void conv_body(
    const u16* __restrict__ Ag, const u16* __restrict__ Wt2g,
    const float* __restrict__ bp,
    u16* __restrict__ qg, u16* __restrict__ dg,
    float* __restrict__ invnq, float* __restrict__ invnd,
    int gram, char* smem)
{
    char* As = smem;                       // [66][656 B]
    char* Bs = smem + 43296;               // [NTAP*8][1024 B]

    const int tid = threadIdx.x;
    const int tile = blockIdx.x;
    const int wv = tid >> 6, lane = tid & 63;
    const int l15 = lane & 15, qd4 = lane >> 4;
    const int mh = wv >> 1, nh = wv & 1;

    // issue B DMA for ks=0
    {
        const char* src = (const char*)Wt2g + lane*16;
        #pragma unroll
        for (int i = 0; i < NTAP*2; ++i) {
            int chunk = wv*NTAP*2 + i;
            gld_lds16(src + chunk*1024, Bs + chunk*1024);
        }
    }
    // stage A: 66 rows x 640 B from pre-gathered Ag
    {
        const char* base = (const char*)Ag + (size_t)tile*64*640;
        #pragma unroll
        for (int i = 0; i < 11; ++i) {
            int idx = tid + i*256;
            if (idx < 2640) {
                int r = idx / 40, c = idx - r*40;
                uint4 v = *(const uint4*)(base + r*640 + c*16);
                *(uint4*)(As + r*656 + c*16) = v;
            }
        }
    }

    float bias[4];
    #pragma unroll
    for (int nt = 0; nt < 4; ++nt) bias[nt] = bp[nh*64 + nt*16 + l15];

    floatx4 acc[2][4];
    #pragma unroll
    for (int mt = 0; mt < 2; ++mt)
        #pragma unroll
        for (int nt = 0; nt < 4; ++nt)
            acc[mt][nt] = (floatx4){0.f,0.f,0.f,0.f};

    __syncthreads();                       // A staged + DMA(0) drained

    short8 af[2][NTAP];
    #pragma unroll
    for (int mt = 0; mt < 2; ++mt)
        #pragma unroll
        for (int j = 0; j < NTAP; ++j)
            af[mt][j] = *(const short8*)(As + (mh*32 + mt*16 + l15 + j)*656 + qd4*16);

    for (int ks = 0; ks < 10; ++ks) {
        #pragma unroll
        for (int j = 0; j < NTAP; ++j) {
            short8 bfj[4];
            #pragma unroll
            for (int nt = 0; nt < 4; ++nt)
                bfj[nt] = *(const short8*)(Bs + (j*8 + nh*4 + nt)*1024 + lane*16);
            #pragma unroll
            for (int mt = 0; mt < 2; ++mt)
                #pragma unroll
                for (int nt = 0; nt < 4; ++nt)
                    acc[mt][nt] = __builtin_amdgcn_mfma_f32_16x16x32_bf16(
                        af[mt][j], bfj[nt], acc[mt][nt], 0, 0, 0);
        }
        if (ks < 9) {
            __syncthreads();               // B reads of ks done
            const char* src = (const char*)Wt2g + (ks+1)*NTAP*8192 + lane*16;
            #pragma unroll
            for (int i = 0; i < NTAP*2; ++i) {
                int chunk = wv*NTAP*2 + i;
                gld_lds16(src + chunk*1024, Bs + chunk*1024);
            }
            #pragma unroll
            for (int mt = 0; mt < 2; ++mt)
                #pragma unroll
                for (int j = 0; j < NTAP; ++j)
                    af[mt][j] = *(const short8*)(As + (mh*32 + mt*16 + l15 + j)*656 + (ks+1)*64 + qd4*16);
            __syncthreads();               // DMA(ks+1) drained
        }
    }
    __syncthreads();                       // last B reads done; overlay Gs

    u16* Gs = (u16*)Bs;                    // [64][136]
    #pragma unroll
    for (int mt = 0; mt < 2; ++mt)
        #pragma unroll
        for (int nt = 0; nt < 4; ++nt) {
            int ch = nh*64 + nt*16 + l15;
            #pragma unroll
            for (int i = 0; i < 4; ++i) {
                int row = mh*32 + mt*16 + qd4*4 + i;
                Gs[row*136 + ch] = f2b(fmaxf(acc[mt][nt][i] + bias[nt], 0.f));
            }
        }
    __syncthreads();

    if (tid < 64) {                        // row inverse-norms from bf16 values
        const char* rp = (const char*)Gs + tid*272;
        float ssum = 0.f;
        #pragma unroll
        for (int t16 = 0; t16 < 16; ++t16) {
            uint4 u = *(const uint4*)(rp + t16*16);
            float x;
            x = bits2f(u.x << 16); ssum += x*x;  x = bits2f(u.x & 0xffff0000u); ssum += x*x;
            x = bits2f(u.y << 16); ssum += x*x;  x = bits2f(u.y & 0xffff0000u); ssum += x*x;
            x = bits2f(u.z << 16); ssum += x*x;  x = bits2f(u.z & 0xffff0000u); ssum += x*x;
            x = bits2f(u.w << 16); ssum += x*x;  x = bits2f(u.w & 0xffff0000u); ssum += x*x;
        }
        float inv = 1.f / (sqrtf(ssum) + 1e-13f);
        int gR = tile*64 + tid;
        int b = gR >> 8, pos = gR & 255;
        if (pos < 208)                     invnd[(gram*B_ + b)*208 + pos] = inv;
        else if (pos < 240)                invnq[(gram*B_ + b)*32 + (pos - 208)] = inv;
    }
    // coalesced copy out
    #pragma unroll
    for (int i = 0; i < 4; ++i) {
        int idx = tid + i*256;             // < 1024 = 64 rows * 16 uint4
        int r = idx >> 4, c16 = idx & 15;
        uint4 v = *(const uint4*)((const char*)Gs + r*272 + c16*16);
        int gR = tile*64 + r;
        int b = gR >> 8, pos = gR & 255;
        if (pos < 208)      *(uint4*)(dg + ((gram*B_ + b)*208 + pos)*128 + c16*8) = v;
        else if (pos < 240) *(uint4*)(qg + ((gram*B_ + b)*32 + (pos - 208))*128 + c16*8) = v;
    }
}

__global__ __launch_bounds__(256, 2) void conv_kernel(
    const u16* __restrict__ Ag, const u16* __restrict__ Wt2,
    const float* __restrict__ b1, const float* __restrict__ b2, const float* __restrict__ b3,
    u16* __restrict__ qg, u16* __restrict__ dg,
    float* __restrict__ invnq, float* __restrict__ invnd)
{
    extern __shared__ char smem[];
    if (blockIdx.y == 0)
        conv_body<1>(Ag, Wt2,                       b1, qg, dg, invnq, invnd, 0, smem);
    else if (blockIdx.y == 1)
        conv_body<2>(Ag, Wt2 + 40960,               b2, qg, dg, invnq, invnd, 1, smem);
    else
        conv_body<3>(Ag, Wt2 + 122880,              b3, qg, dg, invnq, invnd, 2, smem);
}

// ---------------------------------------------------------------------------
// Pool: block = (combo, b); grid (9, 128). Full 208-row d set in static LDS
// (2 blocks/CU), single qi, RBF exp-chain (3 transcendentals), fused
// log+mask+q-reduce -> feats directly.
// ---------------------------------------------------------------------------
__global__ __launch_bounds__(256, 2) void pool_kernel(
    const u16* __restrict__ qg, const u16* __restrict__ dg,
    const float* __restrict__ invnq, const float* __restrict__ invnd,
    const int* __restrict__ qtok, const int* __restrict__ dtok,
    float* __restrict__ feats)
{
    __shared__ __align__(16) u16 dsb[208*136];     // 56576 B
    __shared__ float pk[32*12];
    __shared__ float invq[32];
    __shared__ float qm[32];
    __shared__ __align__(16) float invd[208];

    const int tid = threadIdx.x;
    const int b = blockIdx.y, combo = blockIdx.x;
    const int qi = combo / 3, dj = combo - 3*qi;
    const int wv = tid >> 6, lane = tid & 63;
    const int l15 = lane & 15, qd4 = lane >> 4;

    for (int idx = tid; idx < 208*16; idx += 256) {
        int r = idx >> 4, ch = idx & 15;
        uint4 v = make_uint4(0u,0u,0u,0u);
        if (r < Dn) v = *(const uint4*)(dg + ((dj*B_ + b)*208 + r)*128 + ch*8);
        *(uint4*)((char*)dsb + r*272 + ch*16) = v;
    }
    if (tid < 208) {
        float v = invnd[(dj*B_ + b)*208 + tid];
        bool ok = (tid < Dn) && (dtok[b*Dn + tid] > 0);
        invd[tid] = ok ? v : (-fabsf(v) - 1.0f);   // strictly negative if masked
    }
    if (tid < 32) {
        float v = invnq[(qi*B_ + b)*32 + tid];
        bool ok = (tid < Qn) && (qtok[b*Qn + tid] > 0);
        invq[tid] = ok ? v : 0.f;
        qm[tid] = ok ? 1.f : 0.f;
    }
    for (int i = tid; i < 384; i += 256) pk[i] = 0.f;
    __syncthreads();

    short8 qf[2][4];
    float vq[2];
    #pragma unroll
    for (int qt = 0; qt < 2; ++qt) {
        vq[qt] = invq[qt*16 + l15];
        #pragma unroll
        for (int ks = 0; ks < 4; ++ks)
            qf[qt][ks] = *(const short8*)(qg + ((qi*B_ + b)*32 + qt*16 + l15)*128 + ks*32 + qd4*8);
    }
    float pkl[2][11];
    #pragma unroll
    for (int qt = 0; qt < 2; ++qt)
        #pragma unroll
        for (int k = 0; k < 11; ++k) pkl[qt][k] = 0.f;

    // chain constants C_k = exp(10*(mu_k + mu_{k+1})), mu: 0.9,0.7,...,-0.9
    const float CkR[9] = {8886110.5f, 162754.79f, 2980.958f, 54.598150f, 1.0f,
                          0.018315639f, 3.3546263e-4f, 6.1442124e-6f, 1.1253517e-7f};

    for (int t = wv; t < 13; t += 4) {
        short8 af[4];
        #pragma unroll
        for (int ks = 0; ks < 4; ++ks)
            af[ks] = *(const short8*)((const char*)dsb + (t*16 + l15)*272 + ks*64 + qd4*16);
        floatx4 acc[2];
        acc[0] = (floatx4){0.f,0.f,0.f,0.f};
        acc[1] = (floatx4){0.f,0.f,0.f,0.f};
        #pragma unroll
        for (int ks = 0; ks < 4; ++ks)
            #pragma unroll
            for (int qt = 0; qt < 2; ++qt)
                acc[qt] = __builtin_amdgcn_mfma_f32_16x16x32_bf16(af[ks], qf[qt][ks], acc[qt], 0, 0, 0);
        floatx4 iv4 = *(const floatx4*)(invd + t*16 + qd4*4);
        #pragma unroll
        for (int qt = 0; qt < 2; ++qt)
            #pragma unroll
            for (int i = 0; i < 4; ++i) {
                float cs = acc[qt][i] * vq[qt] * iv4[i];
                cs = (cs > 0.f) ? cs : 2.0f;           // masked/zero -> all kernels ~0
                float t0 = cs - 1.0f;
                float u  = cs - 0.9f;
                float s0 = __expf(-500000.f * t0 * t0);
                float e  = __expf(-50.f * u * u);
                float rr = __expf(-20.f * cs);
                pkl[qt][0] += s0;
                pkl[qt][1] += e;
                #pragma unroll
                for (int kk = 0; kk < 9; ++kk) {
                    e = e * rr * CkR[kk];
                    pkl[qt][2 + kk] += e;
                }
            }
    }
    #pragma unroll
    for (int qt = 0; qt < 2; ++qt)
        #pragma unroll
        for (int k = 0; k < 11; ++k) {
            float v = pkl[qt][k];
            v += __shfl_xor(v, 16);
            v += __shfl_xor(v, 32);
            if (qd4 == 0) atomicAdd(&pk[(qt*16 + l15)*12 + k], v);
        }
    __syncthreads();

    if (tid < 11) {
        float s = 0.f;
        for (int q = 0; q < Qn; ++q)
            s += qm[q] * 0.01f * __logf(fmaxf(pk[q*12 + tid], 1e-10f));
        feats[(b*9 + combo)*11 + tid] = s;
    }
}

// ---------------------------------------------------------------------------
__global__ void final_kernel(const float* __restrict__ feats,
                             const float* __restrict__ dw,
                             float* __restrict__ out) {
    int b = threadIdx.x;
    if (b < B_) {
        float s = 0.f;
        for (int f = 0; f < 99; ++f) s += feats[b*99 + f] * dw[f];
        out[b] = s;
    }
}

extern "C" void kernel_launch(void* const* d_in, const int* in_sizes, int n_in,
                              void* d_out, int out_size, void* d_ws, size_t ws_size,
                              hipStream_t stream) {
    const int*   qtok = (const int*)d_in[0];
    const int*   dtok = (const int*)d_in[1];
    const float* emb  = (const float*)d_in[2];
    const float* w1   = (const float*)d_in[3];
    const float* w2   = (const float*)d_in[4];
    const float* w3   = (const float*)d_in[5];
    const float* b1   = (const float*)d_in[6];
    const float* b2   = (const float*)d_in[7];
    const float* b3   = (const float*)d_in[8];
    const float* dw   = (const float*)d_in[9];
    float* out = (float*)d_out;

    char* w = (char*)d_ws;
    u16*   Wt2   = (u16*)w;                      // 491,520 B
    u16*   Ag    = (u16*)(w + 491520);           // 32770*320*2 = 20,972,800
    u16*   qg    = (u16*)(w + 21464320);         // 3*128*32*128*2  = 3,145,728
    u16*   dgm   = (u16*)(w + 24610048);         // 3*128*208*128*2 = 20,447,232
    float* invq_ = (float*)(w + 45057280);       // 49,152
    float* invd_ = (float*)(w + 45106432);       // 319,488
    float* feats = (float*)(w + 45425920);       // 50,688 -> total 45,476,608

    prep_gather_kernel<<<dim3(24, B_), 256, 0, stream>>>(
        qtok, dtok, emb, w1, w2, w3, Ag, Wt2);

    const int conv_lds = 43296 + 24576;          // 67,872 B -> 2 blocks/CU
    hipFuncSetAttribute(reinterpret_cast<const void*>(conv_kernel),
                        hipFuncAttributeMaxDynamicSharedMemorySize, conv_lds);
    conv_kernel<<<dim3(512, 3), 256, conv_lds, stream>>>(
        Ag, Wt2, b1, b2, b3, qg, dgm, invq_, invd_);

    pool_kernel<<<dim3(9, B_), 256, 0, stream>>>(qg, dgm, invq_, invd_, qtok, dtok, feats);

    final_kernel<<<1, 128, 0, stream>>>(feats, dw, out);
}